// Round 1
// baseline (316.824 us; speedup 1.0000x reference)
//
#include <hip/hip_runtime.h>

#define CH 128

// ---------------- degree / dinv ----------------
__global__ void k_deg(const int* __restrict__ row, int* __restrict__ deg, int E) {
    int e = blockIdx.x * blockDim.x + threadIdx.x;
    if (e < E) atomicAdd(&deg[row[e]], 1);
}

__global__ void k_dinv(const int* __restrict__ deg, float* __restrict__ dinv, int N) {
    int i = blockIdx.x * blockDim.x + threadIdx.x;
    if (i < N) {
        int d = deg[i];
        dinv[i] = (d > 0) ? rsqrtf((float)d) : 0.0f;
    }
}

// ---------------- CSR build: block sums -> scan -> row starts -> fill ----------------
__global__ void k_blocksum(const int* __restrict__ deg, int* __restrict__ bsum, int N) {
    __shared__ int s[256];
    int i = blockIdx.x * 256 + threadIdx.x;
    s[threadIdx.x] = (i < N) ? deg[i] : 0;
    __syncthreads();
    for (int off = 128; off > 0; off >>= 1) {
        if (threadIdx.x < off) s[threadIdx.x] += s[threadIdx.x + off];
        __syncthreads();
    }
    if (threadIdx.x == 0) bsum[blockIdx.x] = s[0];
}

__global__ void k_scanbsum(int* __restrict__ bsum, int nB) {
    // single-thread exclusive scan over ~157 elements; negligible cost
    int run = 0;
    for (int b = 0; b < nB; b++) { int t = bsum[b]; bsum[b] = run; run += t; }
}

__global__ void k_rowstart(const int* __restrict__ deg, const int* __restrict__ bsum,
                           int* __restrict__ rowStart, int N) {
    __shared__ int s[256];
    int i = blockIdx.x * 256 + threadIdx.x;
    int v = (i < N) ? deg[i] : 0;
    s[threadIdx.x] = v;
    __syncthreads();
    // Hillis-Steele inclusive scan
    for (int off = 1; off < 256; off <<= 1) {
        int t = (threadIdx.x >= off) ? s[threadIdx.x - off] : 0;
        __syncthreads();
        s[threadIdx.x] += t;
        __syncthreads();
    }
    if (i < N) {
        int incl = s[threadIdx.x];
        rowStart[i] = bsum[blockIdx.x] + incl - v;
        if (i == N - 1) rowStart[N] = bsum[blockIdx.x] + incl;
    }
}

__global__ void k_fill(const int* __restrict__ row, const int* __restrict__ col,
                       const int* __restrict__ rowStart, int* __restrict__ cursor,
                       int* __restrict__ csr, int E) {
    int e = blockIdx.x * blockDim.x + threadIdx.x;
    if (e < E) {
        int r = row[e];
        int p = atomicAdd(&cursor[r], 1);
        csr[rowStart[r] + p] = col[e];
    }
}

// ---------------- SpMM: out[i][:] = -dinv[i] * sum_{j in N(i)} dinv[j] * X[j][:] ----------------
// One wave (64 lanes) per row; each lane owns 2 channels (float2) -> 512B coalesced per neighbor.
__global__ __launch_bounds__(256) void k_spmm(const float* __restrict__ X,
                                              const float* __restrict__ dinv,
                                              const int* __restrict__ rowStart,
                                              const int* __restrict__ csr,
                                              float* __restrict__ out, int N) {
    int wave = (int)((blockIdx.x * blockDim.x + threadIdx.x) >> 6);
    int lane = threadIdx.x & 63;
    if (wave >= N) return;
    int s = rowStart[wave], e = rowStart[wave + 1];
    const float2* Xp = (const float2*)X;
    float2 acc = make_float2(0.f, 0.f);
    for (int k = s; k < e; ++k) {
        int j = csr[k];
        float w = dinv[j];
        float2 v = Xp[(size_t)j * 64 + lane];
        acc.x += w * v.x;
        acc.y += w * v.y;
    }
    float sc = -dinv[wave];
    float2 r = make_float2(acc.x * sc, acc.y * sc);
    ((float2*)out)[(size_t)wave * 64 + lane] = r;
}

// ---------------- fused GEMM: out = epi(A1@Wa + A2@Wb + bias) ----------------
// K=256 concat GEMM. Block: 64 rows x 128 cols, 256 threads, each thread 8 rows x 4 cols.
// mode 0: out = relu(.)      mode 1: out = 0.5*(xres + relu(.))
__global__ __launch_bounds__(256) void k_gemm(const float* __restrict__ A1,
                                              const float* __restrict__ A2,
                                              const float* __restrict__ Wa,
                                              const float* __restrict__ Wb,
                                              const float* __restrict__ bias,
                                              const float* __restrict__ xres,
                                              float* __restrict__ out, int N, int mode) {
    __shared__ float As[32][68];    // [k][row], pad 68 to spread store banks, float4-aligned rows
    __shared__ float Ws[32][128];   // [k][col]

    const int tid = threadIdx.x;
    const int tx = tid & 31;        // col group: cols 4*tx .. 4*tx+3
    const int ty = tid >> 5;        // row group: rows 8*ty .. 8*ty+7
    const int row0 = blockIdx.x * 64;

    float acc[8][4] = {};

    for (int kt = 0; kt < 8; ++kt) {
        const int k0 = (kt & 3) * 32;
        const float* __restrict__ A = (kt < 4) ? A1 : A2;
        const float* __restrict__ W = (kt < 4) ? Wa : Wb;

        // stage A tile (64 rows x 32 k), transposed into As[k][row]
        #pragma unroll
        for (int it = 0; it < 2; ++it) {
            int idx = tid + it * 256;          // 0..511 float4s
            int r = idx >> 3;                  // 0..63
            int f = idx & 7;                   // float4 within the 32-wide k slab
            const float4 v = *(const float4*)&A[(size_t)(row0 + r) * CH + k0 + f * 4];
            As[f * 4 + 0][r] = v.x;
            As[f * 4 + 1][r] = v.y;
            As[f * 4 + 2][r] = v.z;
            As[f * 4 + 3][r] = v.w;
        }
        // stage W tile (32 k x 128 cols)
        #pragma unroll
        for (int it = 0; it < 4; ++it) {
            int idx = tid + it * 256;          // 0..1023 float4s
            int k = idx >> 5;
            int c4 = idx & 31;
            *(float4*)&Ws[k][c4 * 4] = *(const float4*)&W[(size_t)(k0 + k) * CH + c4 * 4];
        }
        __syncthreads();

        #pragma unroll
        for (int kk = 0; kk < 32; ++kk) {
            float4 a0 = *(const float4*)&As[kk][ty * 8];
            float4 a1 = *(const float4*)&As[kk][ty * 8 + 4];
            float4 w  = *(const float4*)&Ws[kk][tx * 4];
            float av[8] = {a0.x, a0.y, a0.z, a0.w, a1.x, a1.y, a1.z, a1.w};
            float wv[4] = {w.x, w.y, w.z, w.w};
            #pragma unroll
            for (int rr = 0; rr < 8; ++rr)
                #pragma unroll
                for (int cc = 0; cc < 4; ++cc)
                    acc[rr][cc] += av[rr] * wv[cc];
        }
        __syncthreads();
    }

    float bv[4];
    *(float4*)bv = *(const float4*)&bias[tx * 4];

    #pragma unroll
    for (int rr = 0; rr < 8; ++rr) {
        int r = row0 + ty * 8 + rr;
        if (r >= N) break;
        float4 o;
        o.x = fmaxf(acc[rr][0] + bv[0], 0.0f);
        o.y = fmaxf(acc[rr][1] + bv[1], 0.0f);
        o.z = fmaxf(acc[rr][2] + bv[2], 0.0f);
        o.w = fmaxf(acc[rr][3] + bv[3], 0.0f);
        if (mode == 1) {
            const float4 xr = *(const float4*)&xres[(size_t)r * CH + tx * 4];
            o.x = 0.5f * (o.x + xr.x);
            o.y = 0.5f * (o.y + xr.y);
            o.z = 0.5f * (o.z + xr.z);
            o.w = 0.5f * (o.w + xr.w);
        }
        *(float4*)&out[(size_t)r * CH + tx * 4] = o;
    }
}

extern "C" void kernel_launch(void* const* d_in, const int* in_sizes, int n_in,
                              void* d_out, int out_size, void* d_ws, size_t ws_size,
                              hipStream_t stream) {
    const float* x   = (const float*)d_in[0];
    const int*   ei  = (const int*)d_in[1];
    const float* W00 = (const float*)d_in[2];
    const float* W01 = (const float*)d_in[3];
    const float* b0  = (const float*)d_in[4];
    const float* W10 = (const float*)d_in[5];
    const float* W11 = (const float*)d_in[6];
    const float* b1  = (const float*)d_in[7];
    float* out = (float*)d_out;

    const int N = in_sizes[0] / CH;   // 40000
    const int E = in_sizes[1] / 2;    // 640000
    const int* row = ei;
    const int* col = ei + E;

    // workspace carve-out (256B aligned)
    char* ws = (char*)d_ws;
    size_t off = 0;
    auto alloc = [&](size_t bytes) -> void* {
        void* p = ws + off;
        off += (bytes + 255) & ~(size_t)255;
        return p;
    };
    int*   deg      = (int*)alloc((size_t)N * 4);
    float* dinv     = (float*)alloc((size_t)N * 4);
    int*   rowStart = (int*)alloc((size_t)(N + 1) * 4);
    int*   cursor   = (int*)alloc((size_t)N * 4);
    int*   bsum     = (int*)alloc(4096);
    int*   csr      = (int*)alloc((size_t)E * 4);
    float* Lx       = (float*)alloc((size_t)N * CH * 4);
    float* y        = (float*)alloc((size_t)N * CH * 4);

    const int nB = (N + 255) / 256;

    hipMemsetAsync(deg, 0, (size_t)N * 4, stream);
    hipMemsetAsync(cursor, 0, (size_t)N * 4, stream);

    k_deg<<<(E + 255) / 256, 256, 0, stream>>>(row, deg, E);
    k_dinv<<<nB, 256, 0, stream>>>(deg, dinv, N);
    k_blocksum<<<nB, 256, 0, stream>>>(deg, bsum, N);
    k_scanbsum<<<1, 1, 0, stream>>>(bsum, nB);
    k_rowstart<<<nB, 256, 0, stream>>>(deg, bsum, rowStart, N);
    k_fill<<<(E + 255) / 256, 256, 0, stream>>>(row, col, rowStart, cursor, csr, E);

    // layer 1: Lx = L~ x ; y = relu(x@W00 + Lx@W01 + b0)
    k_spmm<<<(N + 3) / 4, 256, 0, stream>>>(x, dinv, rowStart, csr, Lx, N);
    k_gemm<<<(N + 63) / 64, 256, 0, stream>>>(x, Lx, W00, W01, b0, nullptr, y, N, 0);

    // layer 2: Lx = L~ y ; out = 0.5*(x + relu(y@W10 + Lx@W11 + b1))
    k_spmm<<<(N + 3) / 4, 256, 0, stream>>>(y, dinv, rowStart, csr, Lx, N);
    k_gemm<<<(N + 63) / 64, 256, 0, stream>>>(y, Lx, W10, W11, b1, x, out, N, 1);
}

// Round 2
// 197.605 us; speedup vs baseline: 1.6033x; 1.6033x over previous
//
#include <hip/hip_runtime.h>

#define CH 128

typedef unsigned int uint;
typedef unsigned short ushort;
typedef __attribute__((ext_vector_type(8))) short bf16x8;
typedef __attribute__((ext_vector_type(4))) float f32x4;

__device__ inline ushort f2bf(float f) {
    uint u = __float_as_uint(f);
    u += 0x7fffu + ((u >> 16) & 1u);     // RNE
    return (ushort)(u >> 16);
}
__device__ inline float blo(uint v) { return __uint_as_float(v << 16); }
__device__ inline float bhi(uint v) { return __uint_as_float(v & 0xffff0000u); }

// ---------------- degree / dinv ----------------
__global__ void k_deg(const int* __restrict__ row, int* __restrict__ deg, int E) {
    int e = blockIdx.x * blockDim.x + threadIdx.x;
    if (e < E) atomicAdd(&deg[row[e]], 1);
}

__global__ void k_dinv(const int* __restrict__ deg, float* __restrict__ dinv, int N) {
    int i = blockIdx.x * blockDim.x + threadIdx.x;
    if (i < N) {
        int d = deg[i];
        dinv[i] = (d > 0) ? rsqrtf((float)d) : 0.0f;
    }
}

// ---------------- CSR build ----------------
__global__ void k_blocksum(const int* __restrict__ deg, int* __restrict__ bsum, int N) {
    __shared__ int s[256];
    int i = blockIdx.x * 256 + threadIdx.x;
    s[threadIdx.x] = (i < N) ? deg[i] : 0;
    __syncthreads();
    for (int off = 128; off > 0; off >>= 1) {
        if (threadIdx.x < off) s[threadIdx.x] += s[threadIdx.x + off];
        __syncthreads();
    }
    if (threadIdx.x == 0) bsum[blockIdx.x] = s[0];
}

__global__ void k_scanbsum(int* __restrict__ bsum, int nB) {
    int run = 0;
    for (int b = 0; b < nB; b++) { int t = bsum[b]; bsum[b] = run; run += t; }
}

__global__ void k_rowstart(const int* __restrict__ deg, const int* __restrict__ bsum,
                           int* __restrict__ rowStart, int N) {
    __shared__ int s[256];
    int i = blockIdx.x * 256 + threadIdx.x;
    int v = (i < N) ? deg[i] : 0;
    s[threadIdx.x] = v;
    __syncthreads();
    for (int off = 1; off < 256; off <<= 1) {
        int t = (threadIdx.x >= off) ? s[threadIdx.x - off] : 0;
        __syncthreads();
        s[threadIdx.x] += t;
        __syncthreads();
    }
    if (i < N) {
        int incl = s[threadIdx.x];
        rowStart[i] = bsum[blockIdx.x] + incl - v;
        if (i == N - 1) rowStart[N] = bsum[blockIdx.x] + incl;
    }
}

__global__ void k_fill(const int* __restrict__ row, const int* __restrict__ col,
                       const int* __restrict__ rowStart, int* __restrict__ cursor,
                       int* __restrict__ csr, int E) {
    int e = blockIdx.x * blockDim.x + threadIdx.x;
    if (e < E) {
        int r = row[e];
        int p = atomicAdd(&cursor[r], 1);
        csr[rowStart[r] + p] = col[e];
    }
}

// ---------------- conversions ----------------
__global__ void k_cvt_x(const float4* __restrict__ X, uint2* __restrict__ O, int n4) {
    int i = blockIdx.x * 256 + threadIdx.x;
    if (i < n4) {
        float4 v = X[i];
        O[i] = make_uint2((uint)f2bf(v.x) | ((uint)f2bf(v.y) << 16),
                          (uint)f2bf(v.z) | ((uint)f2bf(v.w) << 16));
    }
}

// Wt[col][k] bf16, k = 0..255 (k<128 from Wa, else Wb); packed as uint pairs: Wt[col*128 + k/2]
__global__ void k_cvt_w(const float* __restrict__ Wa, const float* __restrict__ Wb,
                        uint* __restrict__ Wt) {
    int tid = blockIdx.x * 256 + threadIdx.x;
    if (tid >= 128 * 128) return;
    int col = tid & 127, kp = tid >> 7;
    int k = kp * 2;
    const float* W = (k < 128) ? Wa : Wb;
    int kk = k & 127;
    float f0 = W[(size_t)kk * 128 + col];
    float f1 = W[(size_t)(kk + 1) * 128 + col];
    Wt[(size_t)col * 128 + kp] = (uint)f2bf(f0) | ((uint)f2bf(f1) << 16);
}

// ---------------- SpMM (bf16 gather): Ob[i] = bf16( -dinv[i] * sum_j dinv[j] * Xb[j] ) ----------------
// one wave per row, lane owns 2 channels (one packed uint), neighbor loop unrolled x4
__global__ __launch_bounds__(256) void k_spmm_bf16(const uint* __restrict__ Xb,
                                                   const float* __restrict__ dinv,
                                                   const int* __restrict__ rowStart,
                                                   const int* __restrict__ csr,
                                                   uint* __restrict__ Ob, int N) {
    int wv = (int)((blockIdx.x * 256 + threadIdx.x) >> 6);
    int lane = threadIdx.x & 63;
    if (wv >= N) return;
    int s = rowStart[wv], e = rowStart[wv + 1];
    float ax = 0.f, ay = 0.f;
    int k = s;
    for (; k + 4 <= e; k += 4) {
        int j0 = csr[k + 0], j1 = csr[k + 1], j2 = csr[k + 2], j3 = csr[k + 3];
        float w0 = dinv[j0], w1 = dinv[j1], w2 = dinv[j2], w3 = dinv[j3];
        uint v0 = Xb[(size_t)j0 * 64 + lane];
        uint v1 = Xb[(size_t)j1 * 64 + lane];
        uint v2 = Xb[(size_t)j2 * 64 + lane];
        uint v3 = Xb[(size_t)j3 * 64 + lane];
        ax += w0 * blo(v0); ay += w0 * bhi(v0);
        ax += w1 * blo(v1); ay += w1 * bhi(v1);
        ax += w2 * blo(v2); ay += w2 * bhi(v2);
        ax += w3 * blo(v3); ay += w3 * bhi(v3);
    }
    for (; k < e; ++k) {
        int j = csr[k];
        float w = dinv[j];
        uint v = Xb[(size_t)j * 64 + lane];
        ax += w * blo(v); ay += w * bhi(v);
    }
    float sc = -dinv[wv];
    Ob[(size_t)wv * 64 + lane] = (uint)f2bf(ax * sc) | ((uint)f2bf(ay * sc) << 16);
}

// ---------------- MFMA GEMM: out = epi( [A1|A2] @ Wt^T + bias ) ----------------
// A1,A2: [N][128] bf16 (uint-packed). Wt: [128 cols][256 k] bf16 (uint-packed).
// Block tile 128x128, 8 waves (4 row-groups x 2 col-groups), wave tile 32x64.
// mode 0: store bf16 relu(.)    mode 1: store f32 0.5*(xres + relu(.))
__global__ __launch_bounds__(512) void k_gemm_mfma(const uint* __restrict__ A1,
                                                   const uint* __restrict__ A2,
                                                   const uint* __restrict__ Wt,
                                                   const float* __restrict__ bias,
                                                   const float* __restrict__ xres,
                                                   void* __restrict__ outp,
                                                   int N, int mode) {
    // padded row stride 20 uints (40 bf16): bank-friendly, 16B aligned
    __shared__ uint AsU[2][128 * 20];
    __shared__ uint WsU[2][128 * 20];

    const int tid = threadIdx.x;
    const int lane = tid & 63;
    const int wid = tid >> 6;       // 0..7
    const int wr = wid >> 1;        // 0..3
    const int wc = wid & 1;         // 0..1
    const int row0 = blockIdx.x * 128;
    const int l16 = lane & 15;
    const int lk = lane >> 4;       // 0..3

    f32x4 acc[2][4];
    #pragma unroll
    for (int m = 0; m < 2; m++)
        #pragma unroll
        for (int n = 0; n < 4; n++)
            acc[m][n] = (f32x4){0.f, 0.f, 0.f, 0.f};

    const int sr = tid >> 2;        // 0..127 (A row / W col)
    const int sc4 = tid & 3;        // 0..3  (16B chunk within 32-k slab)
    const uint4* A1p = (const uint4*)A1;
    const uint4* A2p = (const uint4*)A2;
    const uint4* Wtp = (const uint4*)Wt;
    const int arow = min(row0 + sr, N - 1);

    uint4 ga, gw;
    {
        ga = A1p[(size_t)arow * 16 + sc4];
        gw = Wtp[(size_t)sr * 32 + sc4];
        *(uint4*)&AsU[0][sr * 20 + sc4 * 4] = ga;
        *(uint4*)&WsU[0][sr * 20 + sc4 * 4] = gw;
    }
    __syncthreads();

    for (int t = 0; t < 8; ++t) {
        const int cur = t & 1;
        if (t < 7) {
            const int k0 = (t + 1) * 32;
            const uint4* Ap = (k0 < 128) ? A1p : A2p;
            const int kk = k0 & 127;
            ga = Ap[(size_t)arow * 16 + (kk >> 3) + sc4];
            gw = Wtp[(size_t)sr * 32 + (k0 >> 3) + sc4];
        }

        bf16x8 bfr[4];
        #pragma unroll
        for (int n = 0; n < 4; n++) {
            int col = wc * 64 + n * 16 + l16;
            bfr[n] = *(const bf16x8*)&WsU[cur][col * 20 + lk * 4];
        }
        #pragma unroll
        for (int m = 0; m < 2; m++) {
            int row = wr * 32 + m * 16 + l16;
            bf16x8 afr = *(const bf16x8*)&AsU[cur][row * 20 + lk * 4];
            #pragma unroll
            for (int n = 0; n < 4; n++)
                acc[m][n] = __builtin_amdgcn_mfma_f32_16x16x32_bf16(afr, bfr[n], acc[m][n], 0, 0, 0);
        }

        if (t < 7) {
            *(uint4*)&AsU[cur ^ 1][sr * 20 + sc4 * 4] = ga;
            *(uint4*)&WsU[cur ^ 1][sr * 20 + sc4 * 4] = gw;
            __syncthreads();
        }
    }

    if (mode == 0) {
        ushort* O = (ushort*)outp;
        #pragma unroll
        for (int m = 0; m < 2; m++) {
            #pragma unroll
            for (int n = 0; n < 4; n++) {
                const int col = wc * 64 + n * 16 + l16;
                const float bn = bias[col];
                #pragma unroll
                for (int r = 0; r < 4; r++) {
                    int rg = row0 + wr * 32 + m * 16 + lk * 4 + r;
                    if (rg < N) {
                        float v = fmaxf(acc[m][n][r] + bn, 0.f);
                        O[(size_t)rg * 128 + col] = f2bf(v);
                    }
                }
            }
        }
    } else {
        float* O = (float*)outp;
        #pragma unroll
        for (int m = 0; m < 2; m++) {
            #pragma unroll
            for (int n = 0; n < 4; n++) {
                const int col = wc * 64 + n * 16 + l16;
                const float bn = bias[col];
                #pragma unroll
                for (int r = 0; r < 4; r++) {
                    int rg = row0 + wr * 32 + m * 16 + lk * 4 + r;
                    if (rg < N) {
                        float v = fmaxf(acc[m][n][r] + bn, 0.f);
                        O[(size_t)rg * 128 + col] = 0.5f * (v + xres[(size_t)rg * 128 + col]);
                    }
                }
            }
        }
    }
}

extern "C" void kernel_launch(void* const* d_in, const int* in_sizes, int n_in,
                              void* d_out, int out_size, void* d_ws, size_t ws_size,
                              hipStream_t stream) {
    const float* x   = (const float*)d_in[0];
    const int*   ei  = (const int*)d_in[1];
    const float* W00 = (const float*)d_in[2];
    const float* W01 = (const float*)d_in[3];
    const float* b0  = (const float*)d_in[4];
    const float* W10 = (const float*)d_in[5];
    const float* W11 = (const float*)d_in[6];
    const float* b1  = (const float*)d_in[7];
    float* out = (float*)d_out;

    const int N = in_sizes[0] / CH;   // 40000
    const int E = in_sizes[1] / 2;    // 640000
    const int* row = ei;
    const int* col = ei + E;

    char* ws = (char*)d_ws;
    size_t off = 0;
    auto alloc = [&](size_t bytes) -> void* {
        void* p = ws + off;
        off += (bytes + 255) & ~(size_t)255;
        return p;
    };
    int*   deg      = (int*)alloc((size_t)N * 4);
    float* dinv     = (float*)alloc((size_t)N * 4);
    int*   rowStart = (int*)alloc((size_t)(N + 1) * 4);
    int*   cursor   = (int*)alloc((size_t)N * 4);
    int*   bsum     = (int*)alloc(4096);
    int*   csr      = (int*)alloc((size_t)E * 4);
    uint*  xb       = (uint*)alloc((size_t)N * 64 * 4);   // x  bf16
    uint*  Lb       = (uint*)alloc((size_t)N * 64 * 4);   // L~ operand bf16
    uint*  yb       = (uint*)alloc((size_t)N * 64 * 4);   // y  bf16
    uint*  Wt0      = (uint*)alloc(128 * 128 * 4);
    uint*  Wt1      = (uint*)alloc(128 * 128 * 4);

    const int nB = (N + 255) / 256;

    hipMemsetAsync(deg, 0, (size_t)N * 4, stream);
    hipMemsetAsync(cursor, 0, (size_t)N * 4, stream);

    k_deg<<<(E + 255) / 256, 256, 0, stream>>>(row, deg, E);
    k_dinv<<<nB, 256, 0, stream>>>(deg, dinv, N);
    k_blocksum<<<nB, 256, 0, stream>>>(deg, bsum, N);
    k_scanbsum<<<1, 1, 0, stream>>>(bsum, nB);
    k_rowstart<<<nB, 256, 0, stream>>>(deg, bsum, rowStart, N);
    k_fill<<<(E + 255) / 256, 256, 0, stream>>>(row, col, rowStart, cursor, csr, E);

    k_cvt_x<<<(N * 32 + 255) / 256, 256, 0, stream>>>((const float4*)x, (uint2*)xb, N * 32);
    k_cvt_w<<<64, 256, 0, stream>>>(W00, W01, Wt0);
    k_cvt_w<<<64, 256, 0, stream>>>(W10, W11, Wt1);

    const int gemmBlocks = (N + 127) / 128;

    // layer 1
    k_spmm_bf16<<<(N + 3) / 4, 256, 0, stream>>>(xb, dinv, rowStart, csr, Lb, N);
    k_gemm_mfma<<<gemmBlocks, 512, 0, stream>>>(xb, Lb, Wt0, b0, nullptr, (void*)yb, N, 0);

    // layer 2
    k_spmm_bf16<<<(N + 3) / 4, 256, 0, stream>>>(yb, dinv, rowStart, csr, Lb, N);
    k_gemm_mfma<<<gemmBlocks, 512, 0, stream>>>(yb, Lb, Wt1, b1, x, (void*)out, N, 1);
}

// Round 3
// 184.039 us; speedup vs baseline: 1.7215x; 1.0737x over previous
//
#include <hip/hip_runtime.h>

#define CH 128

typedef unsigned int uint;
typedef unsigned short ushort;
typedef __attribute__((ext_vector_type(8))) short bf16x8;
typedef __attribute__((ext_vector_type(4))) float f32x4;

__device__ inline ushort f2bf(float f) {
    uint u = __float_as_uint(f);
    u += 0x7fffu + ((u >> 16) & 1u);     // RNE
    return (ushort)(u >> 16);
}
__device__ inline float blo(uint v) { return __uint_as_float(v << 16); }
__device__ inline float bhi(uint v) { return __uint_as_float(v & 0xffff0000u); }
__device__ inline uint pk(float a, float b) { return (uint)f2bf(a) | ((uint)f2bf(b) << 16); }

// ---------------- zero init (replaces 2x 41us hipMemsetAsync fills) ----------------
__global__ void k_zero(int* __restrict__ a, int* __restrict__ b, int n) {
    int i = blockIdx.x * 256 + threadIdx.x;
    if (i < n) { a[i] = 0; b[i] = 0; }
}

// ---------------- degree / dinv ----------------
__global__ void k_deg(const int* __restrict__ row, int* __restrict__ deg, int E) {
    int e = blockIdx.x * blockDim.x + threadIdx.x;
    if (e < E) atomicAdd(&deg[row[e]], 1);
}

__global__ void k_dinv(const int* __restrict__ deg, float* __restrict__ dinv, int N) {
    int i = blockIdx.x * blockDim.x + threadIdx.x;
    if (i < N) {
        int d = deg[i];
        dinv[i] = (d > 0) ? rsqrtf((float)d) : 0.0f;
    }
}

// ---------------- CSR build ----------------
__global__ void k_blocksum(const int* __restrict__ deg, int* __restrict__ bsum, int N) {
    __shared__ int s[256];
    int i = blockIdx.x * 256 + threadIdx.x;
    s[threadIdx.x] = (i < N) ? deg[i] : 0;
    __syncthreads();
    for (int off = 128; off > 0; off >>= 1) {
        if (threadIdx.x < off) s[threadIdx.x] += s[threadIdx.x + off];
        __syncthreads();
    }
    if (threadIdx.x == 0) bsum[blockIdx.x] = s[0];
}

__global__ void k_scanbsum(int* __restrict__ bsum, int nB) {
    int run = 0;
    for (int b = 0; b < nB; b++) { int t = bsum[b]; bsum[b] = run; run += t; }
}

__global__ void k_rowstart(const int* __restrict__ deg, const int* __restrict__ bsum,
                           int* __restrict__ rowStart, int N) {
    __shared__ int s[256];
    int i = blockIdx.x * 256 + threadIdx.x;
    int v = (i < N) ? deg[i] : 0;
    s[threadIdx.x] = v;
    __syncthreads();
    for (int off = 1; off < 256; off <<= 1) {
        int t = (threadIdx.x >= off) ? s[threadIdx.x - off] : 0;
        __syncthreads();
        s[threadIdx.x] += t;
        __syncthreads();
    }
    if (i < N) {
        int incl = s[threadIdx.x];
        rowStart[i] = bsum[blockIdx.x] + incl - v;
        if (i == N - 1) rowStart[N] = bsum[blockIdx.x] + incl;
    }
}

__global__ void k_fill(const int* __restrict__ row, const int* __restrict__ col,
                       const int* __restrict__ rowStart, int* __restrict__ cursor,
                       int* __restrict__ csr, int E) {
    int e = blockIdx.x * blockDim.x + threadIdx.x;
    if (e < E) {
        int r = row[e];
        int p = atomicAdd(&cursor[r], 1);
        csr[rowStart[r] + p] = col[e];
    }
}

// ---------------- conversions ----------------
// x -> xb (bf16) and xsb (bf16, pre-scaled by dinv[node]) in one pass
__global__ void k_cvt_x(const float4* __restrict__ X, const float* __restrict__ dinv,
                        uint2* __restrict__ Xb, uint2* __restrict__ Xsb, int n4) {
    int i = blockIdx.x * 256 + threadIdx.x;
    if (i >= n4) return;
    float4 v = X[i];
    float s = dinv[i >> 5];
    Xb[i]  = make_uint2(pk(v.x, v.y), pk(v.z, v.w));
    Xsb[i] = make_uint2(pk(v.x * s, v.y * s), pk(v.z * s, v.w * s));
}

// Wt[col][k] bf16, k = 0..255 (k<128 from Wa, else Wb); packed: Wt[col*128 + k/2]
__global__ void k_cvt_w(const float* __restrict__ Wa, const float* __restrict__ Wb,
                        uint* __restrict__ Wt) {
    int tid = blockIdx.x * 256 + threadIdx.x;
    if (tid >= 128 * 128) return;
    int col = tid & 127, kp = tid >> 7;
    int k = kp * 2;
    const float* W = (k < 128) ? Wa : Wb;
    int kk = k & 127;
    float f0 = W[(size_t)kk * 128 + col];
    float f1 = W[(size_t)(kk + 1) * 128 + col];
    Wt[(size_t)col * 128 + kp] = pk(f0, f1);
}

// ---------------- SpMM (pre-scaled gather): Ob[i] = bf16( -dinv[i] * sum_j Xs[j] ) ----------------
// 32 lanes per row (lane owns uint2 = 4 channels), 2 rows per wave, unroll x4.
__global__ __launch_bounds__(256) void k_spmm(const uint2* __restrict__ Xs,
                                              const float* __restrict__ dinv,
                                              const int* __restrict__ rowStart,
                                              const int* __restrict__ csr,
                                              uint2* __restrict__ Ob, int N) {
    int r = (int)((blockIdx.x * 256 + threadIdx.x) >> 5);   // one row per half-wave
    int l = threadIdx.x & 31;
    if (r >= N) return;
    int s = rowStart[r], e = rowStart[r + 1];
    float a0 = 0.f, a1 = 0.f, a2 = 0.f, a3 = 0.f;
    int k = s;
    for (; k + 4 <= e; k += 4) {
        int j0 = csr[k + 0], j1 = csr[k + 1], j2 = csr[k + 2], j3 = csr[k + 3];
        uint2 v0 = Xs[(size_t)j0 * 32 + l];
        uint2 v1 = Xs[(size_t)j1 * 32 + l];
        uint2 v2 = Xs[(size_t)j2 * 32 + l];
        uint2 v3 = Xs[(size_t)j3 * 32 + l];
        a0 += (blo(v0.x) + blo(v1.x)) + (blo(v2.x) + blo(v3.x));
        a1 += (bhi(v0.x) + bhi(v1.x)) + (bhi(v2.x) + bhi(v3.x));
        a2 += (blo(v0.y) + blo(v1.y)) + (blo(v2.y) + blo(v3.y));
        a3 += (bhi(v0.y) + bhi(v1.y)) + (bhi(v2.y) + bhi(v3.y));
    }
    for (; k < e; ++k) {
        int j = csr[k];
        uint2 v = Xs[(size_t)j * 32 + l];
        a0 += blo(v.x); a1 += bhi(v.x); a2 += blo(v.y); a3 += bhi(v.y);
    }
    float sc = -dinv[r];
    Ob[(size_t)r * 32 + l] = make_uint2(pk(a0 * sc, a1 * sc), pk(a2 * sc, a3 * sc));
}

// ---------------- MFMA GEMM: out = epi( [A1|A2] @ Wt^T + bias ) ----------------
// A1,A2: [N][128] bf16 (uint-packed). Wt: [128 cols][256 k] bf16 (uint-packed).
// Block tile 128x128, 8 waves (4x2), wave tile 32x64.
// mode 0: store bf16 relu(.) to outp AND bf16 dinv[r]*relu(.) to outs
// mode 1: store f32 0.5*(xres + relu(.)) to outp
__global__ __launch_bounds__(512) void k_gemm_mfma(const uint* __restrict__ A1,
                                                   const uint* __restrict__ A2,
                                                   const uint* __restrict__ Wt,
                                                   const float* __restrict__ bias,
                                                   const float* __restrict__ xres,
                                                   const float* __restrict__ dinv,
                                                   void* __restrict__ outp,
                                                   uint* __restrict__ outs,
                                                   int N, int mode) {
    __shared__ uint AsU[2][128 * 20];   // stride 20 uints: 2-way LDS aliasing only (free)
    __shared__ uint WsU[2][128 * 20];

    const int tid = threadIdx.x;
    const int lane = tid & 63;
    const int wid = tid >> 6;
    const int wr = wid >> 1;        // 0..3
    const int wc = wid & 1;         // 0..1
    const int row0 = blockIdx.x * 128;
    const int l16 = lane & 15;
    const int lk = lane >> 4;       // 0..3

    f32x4 acc[2][4];
    #pragma unroll
    for (int m = 0; m < 2; m++)
        #pragma unroll
        for (int n = 0; n < 4; n++)
            acc[m][n] = (f32x4){0.f, 0.f, 0.f, 0.f};

    const int sr = tid >> 2;        // 0..127
    const int sc4 = tid & 3;        // 0..3
    const uint4* A1p = (const uint4*)A1;
    const uint4* A2p = (const uint4*)A2;
    const uint4* Wtp = (const uint4*)Wt;
    const int arow = min(row0 + sr, N - 1);

    uint4 ga, gw;
    ga = A1p[(size_t)arow * 16 + sc4];
    gw = Wtp[(size_t)sr * 32 + sc4];
    *(uint4*)&AsU[0][sr * 20 + sc4 * 4] = ga;
    *(uint4*)&WsU[0][sr * 20 + sc4 * 4] = gw;
    __syncthreads();

    for (int t = 0; t < 8; ++t) {
        const int cur = t & 1;
        if (t < 7) {
            const int k0 = (t + 1) * 32;
            const uint4* Ap = (k0 < 128) ? A1p : A2p;
            const int kk = k0 & 127;
            ga = Ap[(size_t)arow * 16 + (kk >> 3) + sc4];
            gw = Wtp[(size_t)sr * 32 + (k0 >> 3) + sc4];
        }

        bf16x8 bfr[4];
        #pragma unroll
        for (int n = 0; n < 4; n++) {
            int col = wc * 64 + n * 16 + l16;
            bfr[n] = *(const bf16x8*)&WsU[cur][col * 20 + lk * 4];
        }
        #pragma unroll
        for (int m = 0; m < 2; m++) {
            int row = wr * 32 + m * 16 + l16;
            bf16x8 afr = *(const bf16x8*)&AsU[cur][row * 20 + lk * 4];
            #pragma unroll
            for (int n = 0; n < 4; n++)
                acc[m][n] = __builtin_amdgcn_mfma_f32_16x16x32_bf16(afr, bfr[n], acc[m][n], 0, 0, 0);
        }

        if (t < 7) {
            *(uint4*)&AsU[cur ^ 1][sr * 20 + sc4 * 4] = ga;
            *(uint4*)&WsU[cur ^ 1][sr * 20 + sc4 * 4] = gw;
            __syncthreads();
        }
    }

    if (mode == 0) {
        ushort* O = (ushort*)outp;
        ushort* S = (ushort*)outs;
        #pragma unroll
        for (int m = 0; m < 2; m++) {
            #pragma unroll
            for (int r = 0; r < 4; r++) {
                int rg = row0 + wr * 32 + m * 16 + lk * 4 + r;
                if (rg >= N) continue;
                float sc = dinv[rg];
                #pragma unroll
                for (int n = 0; n < 4; n++) {
                    const int col = wc * 64 + n * 16 + l16;
                    float v = fmaxf(acc[m][n][r] + bias[col], 0.f);
                    O[(size_t)rg * 128 + col] = f2bf(v);
                    S[(size_t)rg * 128 + col] = f2bf(v * sc);
                }
            }
        }
    } else {
        float* O = (float*)outp;
        #pragma unroll
        for (int m = 0; m < 2; m++) {
            #pragma unroll
            for (int r = 0; r < 4; r++) {
                int rg = row0 + wr * 32 + m * 16 + lk * 4 + r;
                if (rg >= N) continue;
                #pragma unroll
                for (int n = 0; n < 4; n++) {
                    const int col = wc * 64 + n * 16 + l16;
                    float v = fmaxf(acc[m][n][r] + bias[col], 0.f);
                    O[(size_t)rg * 128 + col] = 0.5f * (v + xres[(size_t)rg * 128 + col]);
                }
            }
        }
    }
}

extern "C" void kernel_launch(void* const* d_in, const int* in_sizes, int n_in,
                              void* d_out, int out_size, void* d_ws, size_t ws_size,
                              hipStream_t stream) {
    const float* x   = (const float*)d_in[0];
    const int*   ei  = (const int*)d_in[1];
    const float* W00 = (const float*)d_in[2];
    const float* W01 = (const float*)d_in[3];
    const float* b0  = (const float*)d_in[4];
    const float* W10 = (const float*)d_in[5];
    const float* W11 = (const float*)d_in[6];
    const float* b1  = (const float*)d_in[7];
    float* out = (float*)d_out;

    const int N = in_sizes[0] / CH;   // 40000
    const int E = in_sizes[1] / 2;    // 640000
    const int* row = ei;
    const int* col = ei + E;

    char* ws = (char*)d_ws;
    size_t off = 0;
    auto alloc = [&](size_t bytes) -> void* {
        void* p = ws + off;
        off += (bytes + 255) & ~(size_t)255;
        return p;
    };
    int*   deg      = (int*)alloc((size_t)N * 4);
    float* dinv     = (float*)alloc((size_t)N * 4);
    int*   rowStart = (int*)alloc((size_t)(N + 1) * 4);
    int*   cursor   = (int*)alloc((size_t)N * 4);
    int*   bsum     = (int*)alloc(4096);
    int*   csr      = (int*)alloc((size_t)E * 4);
    uint*  xb       = (uint*)alloc((size_t)N * 64 * 4);   // x bf16 (GEMM operand)
    uint*  xsb      = (uint*)alloc((size_t)N * 64 * 4);   // dinv*x bf16 (gather operand)
    uint*  Lb       = (uint*)alloc((size_t)N * 64 * 4);   // L~ result bf16
    uint*  yb       = (uint*)alloc((size_t)N * 64 * 4);   // y bf16 (GEMM operand)
    uint*  ysb      = (uint*)alloc((size_t)N * 64 * 4);   // dinv*y bf16 (gather operand)
    uint*  Wt0      = (uint*)alloc(128 * 128 * 4);
    uint*  Wt1      = (uint*)alloc(128 * 128 * 4);

    const int nB = (N + 255) / 256;

    k_zero<<<nB, 256, 0, stream>>>(deg, cursor, N);
    k_deg<<<(E + 255) / 256, 256, 0, stream>>>(row, deg, E);
    k_dinv<<<nB, 256, 0, stream>>>(deg, dinv, N);
    k_blocksum<<<nB, 256, 0, stream>>>(deg, bsum, N);
    k_scanbsum<<<1, 1, 0, stream>>>(bsum, nB);
    k_rowstart<<<nB, 256, 0, stream>>>(deg, bsum, rowStart, N);
    k_fill<<<(E + 255) / 256, 256, 0, stream>>>(row, col, rowStart, cursor, csr, E);

    k_cvt_x<<<(N * 32 + 255) / 256, 256, 0, stream>>>((const float4*)x, dinv,
                                                      (uint2*)xb, (uint2*)xsb, N * 32);
    k_cvt_w<<<64, 256, 0, stream>>>(W00, W01, Wt0);
    k_cvt_w<<<64, 256, 0, stream>>>(W10, W11, Wt1);

    const int gemmBlocks = (N + 127) / 128;

    // layer 1
    k_spmm<<<(N + 7) / 8, 256, 0, stream>>>((const uint2*)xsb, dinv, rowStart, csr,
                                            (uint2*)Lb, N);
    k_gemm_mfma<<<gemmBlocks, 512, 0, stream>>>(xb, Lb, Wt0, b0, nullptr, dinv,
                                                (void*)yb, ysb, N, 0);

    // layer 2
    k_spmm<<<(N + 7) / 8, 256, 0, stream>>>((const uint2*)ysb, dinv, rowStart, csr,
                                            (uint2*)Lb, N);
    k_gemm_mfma<<<gemmBlocks, 512, 0, stream>>>(yb, Lb, Wt1, b1, x, dinv,
                                                (void*)out, nullptr, N, 1);
}

// Round 4
// 144.003 us; speedup vs baseline: 2.2001x; 1.2780x over previous
//
#include <hip/hip_runtime.h>

#define CH 128

typedef unsigned int uint;
typedef unsigned short ushort;
typedef __attribute__((ext_vector_type(8))) short bf16x8;
typedef __attribute__((ext_vector_type(4))) float f32x4;

__device__ inline ushort f2bf(float f) {
    uint u = __float_as_uint(f);
    u += 0x7fffu + ((u >> 16) & 1u);     // RNE
    return (ushort)(u >> 16);
}
__device__ inline float blo(uint v) { return __uint_as_float(v << 16); }
__device__ inline float bhi(uint v) { return __uint_as_float(v & 0xffff0000u); }
__device__ inline uint pk(float a, float b) { return (uint)f2bf(a) | ((uint)f2bf(b) << 16); }

// ---------------- zero deg ----------------
__global__ void k_zero(int* __restrict__ a, int n) {
    int i = blockIdx.x * 256 + threadIdx.x;
    if (i < n) a[i] = 0;
}

// ---------------- degree + per-edge slot ----------------
__global__ void k_deg(const int* __restrict__ row, int* __restrict__ deg,
                      int* __restrict__ pos, int E) {
    int e = blockIdx.x * blockDim.x + threadIdx.x;
    if (e < E) pos[e] = atomicAdd(&deg[row[e]], 1);
}

// ---------------- dinv + per-block degree sums (merged) ----------------
__global__ void k_dinv_bsum(const int* __restrict__ deg, float* __restrict__ dinv,
                            int* __restrict__ bsum, int N) {
    __shared__ int s[256];
    int i = blockIdx.x * 256 + threadIdx.x;
    int d = (i < N) ? deg[i] : 0;
    if (i < N) dinv[i] = (d > 0) ? rsqrtf((float)d) : 0.0f;
    s[threadIdx.x] = d;
    __syncthreads();
    for (int off = 128; off > 0; off >>= 1) {
        if (threadIdx.x < off) s[threadIdx.x] += s[threadIdx.x + off];
        __syncthreads();
    }
    if (threadIdx.x == 0) bsum[blockIdx.x] = s[0];
}

// ---------------- parallel exclusive scan of block sums (nB <= 256) ----------------
__global__ void k_scan(int* __restrict__ bsum, int nB) {
    __shared__ int s[256];
    int v = (threadIdx.x < nB) ? bsum[threadIdx.x] : 0;
    s[threadIdx.x] = v;
    __syncthreads();
    for (int off = 1; off < 256; off <<= 1) {
        int t = (threadIdx.x >= off) ? s[threadIdx.x - off] : 0;
        __syncthreads();
        s[threadIdx.x] += t;
        __syncthreads();
    }
    if (threadIdx.x < nB) bsum[threadIdx.x] = s[threadIdx.x] - v;   // exclusive
}

__global__ void k_rowstart(const int* __restrict__ deg, const int* __restrict__ bsum,
                           int* __restrict__ rowStart, int N) {
    __shared__ int s[256];
    int i = blockIdx.x * 256 + threadIdx.x;
    int v = (i < N) ? deg[i] : 0;
    s[threadIdx.x] = v;
    __syncthreads();
    for (int off = 1; off < 256; off <<= 1) {
        int t = (threadIdx.x >= off) ? s[threadIdx.x - off] : 0;
        __syncthreads();
        s[threadIdx.x] += t;
        __syncthreads();
    }
    if (i < N) {
        int incl = s[threadIdx.x];
        rowStart[i] = bsum[blockIdx.x] + incl - v;
        if (i == N - 1) rowStart[N] = bsum[blockIdx.x] + incl;
    }
}

// ---------------- CSR fill: pure scatter, no atomics ----------------
__global__ void k_fill(const int* __restrict__ row, const int* __restrict__ col,
                       const int* __restrict__ rowStart, const int* __restrict__ pos,
                       int* __restrict__ csr, int E) {
    int e = blockIdx.x * blockDim.x + threadIdx.x;
    if (e < E) csr[rowStart[row[e]] + pos[e]] = col[e];
}

// ---------------- conversions ----------------
__global__ void k_cvt_x(const float4* __restrict__ X, const float* __restrict__ dinv,
                        uint2* __restrict__ Xb, uint2* __restrict__ Xsb, int n4) {
    int i = blockIdx.x * 256 + threadIdx.x;
    if (i >= n4) return;
    float4 v = X[i];
    float s = dinv[i >> 5];
    Xb[i]  = make_uint2(pk(v.x, v.y), pk(v.z, v.w));
    Xsb[i] = make_uint2(pk(v.x * s, v.y * s), pk(v.z * s, v.w * s));
}

// both layers' weights in one launch: 128 blocks x 256 = 32768 = 2 * 128*128/1 threads
__global__ void k_cvt_w(const float* __restrict__ W00, const float* __restrict__ W01,
                        const float* __restrict__ W10, const float* __restrict__ W11,
                        uint* __restrict__ Wt0, uint* __restrict__ Wt1) {
    int tid = blockIdx.x * 256 + threadIdx.x;        // 0..32767
    int which = tid >> 14;                            // 0 or 1
    int t = tid & 16383;                              // 0..16383
    int col = t & 127, kp = t >> 7;
    int k = kp * 2;
    const float* W = (which == 0) ? ((k < 128) ? W00 : W01) : ((k < 128) ? W10 : W11);
    uint* Wt = (which == 0) ? Wt0 : Wt1;
    int kk = k & 127;
    float f0 = W[(size_t)kk * 128 + col];
    float f1 = W[(size_t)(kk + 1) * 128 + col];
    Wt[(size_t)col * 128 + kp] = pk(f0, f1);
}

// ---------------- SpMM (pre-scaled gather): Ob[i] = bf16( -dinv[i] * sum_j Xs[j] ) ----------------
__global__ __launch_bounds__(256) void k_spmm(const uint2* __restrict__ Xs,
                                              const float* __restrict__ dinv,
                                              const int* __restrict__ rowStart,
                                              const int* __restrict__ csr,
                                              uint2* __restrict__ Ob, int N) {
    int r = (int)((blockIdx.x * 256 + threadIdx.x) >> 5);   // one row per 32 lanes
    int l = threadIdx.x & 31;
    if (r >= N) return;
    int s = rowStart[r], e = rowStart[r + 1];
    float a0 = 0.f, a1 = 0.f, a2 = 0.f, a3 = 0.f;
    int k = s;
    for (; k + 4 <= e; k += 4) {
        int j0 = csr[k + 0], j1 = csr[k + 1], j2 = csr[k + 2], j3 = csr[k + 3];
        uint2 v0 = Xs[(size_t)j0 * 32 + l];
        uint2 v1 = Xs[(size_t)j1 * 32 + l];
        uint2 v2 = Xs[(size_t)j2 * 32 + l];
        uint2 v3 = Xs[(size_t)j3 * 32 + l];
        a0 += (blo(v0.x) + blo(v1.x)) + (blo(v2.x) + blo(v3.x));
        a1 += (bhi(v0.x) + bhi(v1.x)) + (bhi(v2.x) + bhi(v3.x));
        a2 += (blo(v0.y) + blo(v1.y)) + (blo(v2.y) + blo(v3.y));
        a3 += (bhi(v0.y) + bhi(v1.y)) + (bhi(v2.y) + bhi(v3.y));
    }
    for (; k < e; ++k) {
        int j = csr[k];
        uint2 v = Xs[(size_t)j * 32 + l];
        a0 += blo(v.x); a1 += bhi(v.x); a2 += blo(v.y); a3 += bhi(v.y);
    }
    float sc = -dinv[r];
    Ob[(size_t)r * 32 + l] = make_uint2(pk(a0 * sc, a1 * sc), pk(a2 * sc, a3 * sc));
}

// ---------------- MFMA GEMM: out = epi( [A1|A2] @ Wt^T + bias ) ----------------
__global__ __launch_bounds__(512) void k_gemm_mfma(const uint* __restrict__ A1,
                                                   const uint* __restrict__ A2,
                                                   const uint* __restrict__ Wt,
                                                   const float* __restrict__ bias,
                                                   const float* __restrict__ xres,
                                                   const float* __restrict__ dinv,
                                                   void* __restrict__ outp,
                                                   uint* __restrict__ outs,
                                                   int N, int mode) {
    __shared__ uint AsU[2][128 * 20];
    __shared__ uint WsU[2][128 * 20];

    const int tid = threadIdx.x;
    const int lane = tid & 63;
    const int wid = tid >> 6;
    const int wr = wid >> 1;
    const int wc = wid & 1;
    const int row0 = blockIdx.x * 128;
    const int l16 = lane & 15;
    const int lk = lane >> 4;

    f32x4 acc[2][4];
    #pragma unroll
    for (int m = 0; m < 2; m++)
        #pragma unroll
        for (int n = 0; n < 4; n++)
            acc[m][n] = (f32x4){0.f, 0.f, 0.f, 0.f};

    const int sr = tid >> 2;
    const int sc4 = tid & 3;
    const uint4* A1p = (const uint4*)A1;
    const uint4* A2p = (const uint4*)A2;
    const uint4* Wtp = (const uint4*)Wt;
    const int arow = min(row0 + sr, N - 1);

    uint4 ga, gw;
    ga = A1p[(size_t)arow * 16 + sc4];
    gw = Wtp[(size_t)sr * 32 + sc4];
    *(uint4*)&AsU[0][sr * 20 + sc4 * 4] = ga;
    *(uint4*)&WsU[0][sr * 20 + sc4 * 4] = gw;
    __syncthreads();

    for (int t = 0; t < 8; ++t) {
        const int cur = t & 1;
        if (t < 7) {
            const int k0 = (t + 1) * 32;
            const uint4* Ap = (k0 < 128) ? A1p : A2p;
            const int kk = k0 & 127;
            ga = Ap[(size_t)arow * 16 + (kk >> 3) + sc4];
            gw = Wtp[(size_t)sr * 32 + (k0 >> 3) + sc4];
        }

        bf16x8 bfr[4];
        #pragma unroll
        for (int n = 0; n < 4; n++) {
            int col = wc * 64 + n * 16 + l16;
            bfr[n] = *(const bf16x8*)&WsU[cur][col * 20 + lk * 4];
        }
        #pragma unroll
        for (int m = 0; m < 2; m++) {
            int row = wr * 32 + m * 16 + l16;
            bf16x8 afr = *(const bf16x8*)&AsU[cur][row * 20 + lk * 4];
            #pragma unroll
            for (int n = 0; n < 4; n++)
                acc[m][n] = __builtin_amdgcn_mfma_f32_16x16x32_bf16(afr, bfr[n], acc[m][n], 0, 0, 0);
        }

        if (t < 7) {
            *(uint4*)&AsU[cur ^ 1][sr * 20 + sc4 * 4] = ga;
            *(uint4*)&WsU[cur ^ 1][sr * 20 + sc4 * 4] = gw;
            __syncthreads();
        }
    }

    if (mode == 0) {
        ushort* O = (ushort*)outp;
        ushort* S = (ushort*)outs;
        #pragma unroll
        for (int m = 0; m < 2; m++) {
            #pragma unroll
            for (int r = 0; r < 4; r++) {
                int rg = row0 + wr * 32 + m * 16 + lk * 4 + r;
                if (rg >= N) continue;
                float sc = dinv[rg];
                #pragma unroll
                for (int n = 0; n < 4; n++) {
                    const int col = wc * 64 + n * 16 + l16;
                    float v = fmaxf(acc[m][n][r] + bias[col], 0.f);
                    O[(size_t)rg * 128 + col] = f2bf(v);
                    S[(size_t)rg * 128 + col] = f2bf(v * sc);
                }
            }
        }
    } else {
        float* O = (float*)outp;
        #pragma unroll
        for (int m = 0; m < 2; m++) {
            #pragma unroll
            for (int r = 0; r < 4; r++) {
                int rg = row0 + wr * 32 + m * 16 + lk * 4 + r;
                if (rg >= N) continue;
                #pragma unroll
                for (int n = 0; n < 4; n++) {
                    const int col = wc * 64 + n * 16 + l16;
                    float v = fmaxf(acc[m][n][r] + bias[col], 0.f);
                    O[(size_t)rg * 128 + col] = 0.5f * (v + xres[(size_t)rg * 128 + col]);
                }
            }
        }
    }
}

extern "C" void kernel_launch(void* const* d_in, const int* in_sizes, int n_in,
                              void* d_out, int out_size, void* d_ws, size_t ws_size,
                              hipStream_t stream) {
    const float* x   = (const float*)d_in[0];
    const int*   ei  = (const int*)d_in[1];
    const float* W00 = (const float*)d_in[2];
    const float* W01 = (const float*)d_in[3];
    const float* b0  = (const float*)d_in[4];
    const float* W10 = (const float*)d_in[5];
    const float* W11 = (const float*)d_in[6];
    const float* b1  = (const float*)d_in[7];
    float* out = (float*)d_out;

    const int N = in_sizes[0] / CH;   // 40000
    const int E = in_sizes[1] / 2;    // 640000
    const int* row = ei;
    const int* col = ei + E;

    char* ws = (char*)d_ws;
    size_t off = 0;
    auto alloc = [&](size_t bytes) -> void* {
        void* p = ws + off;
        off += (bytes + 255) & ~(size_t)255;
        return p;
    };
    int*   deg      = (int*)alloc((size_t)N * 4);
    float* dinv     = (float*)alloc((size_t)N * 4);
    int*   rowStart = (int*)alloc((size_t)(N + 1) * 4);
    int*   pos      = (int*)alloc((size_t)E * 4);
    int*   bsum     = (int*)alloc(4096);
    int*   csr      = (int*)alloc((size_t)E * 4);
    uint*  xb       = (uint*)alloc((size_t)N * 64 * 4);
    uint*  xsb      = (uint*)alloc((size_t)N * 64 * 4);
    uint*  Lb       = (uint*)alloc((size_t)N * 64 * 4);
    uint*  yb       = (uint*)alloc((size_t)N * 64 * 4);
    uint*  ysb      = (uint*)alloc((size_t)N * 64 * 4);
    uint*  Wt0      = (uint*)alloc(128 * 128 * 4);
    uint*  Wt1      = (uint*)alloc(128 * 128 * 4);

    const int nB = (N + 255) / 256;   // 157 <= 256

    k_zero<<<nB, 256, 0, stream>>>(deg, N);
    k_deg<<<(E + 255) / 256, 256, 0, stream>>>(row, deg, pos, E);
    k_dinv_bsum<<<nB, 256, 0, stream>>>(deg, dinv, bsum, N);
    k_scan<<<1, 256, 0, stream>>>(bsum, nB);
    k_rowstart<<<nB, 256, 0, stream>>>(deg, bsum, rowStart, N);
    k_fill<<<(E + 255) / 256, 256, 0, stream>>>(row, col, rowStart, pos, csr, E);

    k_cvt_x<<<(N * 32 + 255) / 256, 256, 0, stream>>>((const float4*)x, dinv,
                                                      (uint2*)xb, (uint2*)xsb, N * 32);
    k_cvt_w<<<128, 256, 0, stream>>>(W00, W01, W10, W11, Wt0, Wt1);

    const int gemmBlocks = (N + 127) / 128;

    // layer 1
    k_spmm<<<(N + 7) / 8, 256, 0, stream>>>((const uint2*)xsb, dinv, rowStart, csr,
                                            (uint2*)Lb, N);
    k_gemm_mfma<<<gemmBlocks, 512, 0, stream>>>(xb, Lb, Wt0, b0, nullptr, dinv,
                                                (void*)yb, ysb, N, 0);

    // layer 2
    k_spmm<<<(N + 7) / 8, 256, 0, stream>>>((const uint2*)ysb, dinv, rowStart, csr,
                                            (uint2*)Lb, N);
    k_gemm_mfma<<<gemmBlocks, 512, 0, stream>>>(yb, Lb, Wt1, b1, x, dinv,
                                                (void*)out, nullptr, N, 1);
}